// Round 1
// baseline (1300.647 us; speedup 1.0000x reference)
//
#include <hip/hip_runtime.h>

#define N_NODES_C 100000
#define N_EDGES_C 600000
#define HIDDEN_C 128
#define ALPHA_C 0.1f
#define K_HOPS_C 10

// ---------------- degree count (in-degree over real edges) ----------------
__global__ void k_deg(const int* __restrict__ dst, int* __restrict__ deg, int E) {
    int e = blockIdx.x * blockDim.x + threadIdx.x;
    if (e < E) atomicAdd(&deg[dst[e]], 1);
}

// ------- single-block scan: offs = exclusive scan(deg); cursor = copy; -----
// ------- dinv[i] = rsqrt(deg[i] + 1)  (+1 = self-loop)                 -----
__global__ __launch_bounds__(1024) void k_scan(const int* __restrict__ deg,
                                               int* __restrict__ offs,
                                               int* __restrict__ cursor,
                                               float* __restrict__ dinv, int N) {
    __shared__ int wtot[16];
    int tid = threadIdx.x;
    int lane = tid & 63;
    int wid = tid >> 6;
    int carry = 0;
    for (int base = 0; base < N; base += 1024) {
        int i = base + tid;
        int v = (i < N) ? deg[i] : 0;
        if (i < N) dinv[i] = rsqrtf((float)(v + 1));
        // wave-64 inclusive scan via shuffles (no syncs)
        int incl = v;
#pragma unroll
        for (int d = 1; d < 64; d <<= 1) {
            int t = __shfl_up(incl, (unsigned)d, 64);
            if (lane >= d) incl += t;
        }
        if (lane == 63) wtot[wid] = incl;
        __syncthreads();
        int woff = 0, btot = 0;
#pragma unroll
        for (int w = 0; w < 16; ++w) {
            int t = wtot[w];
            if (w < wid) woff += t;
            btot += t;
        }
        int excl = woff + incl - v;
        if (i < N) {
            offs[i] = carry + excl;
            cursor[i] = carry + excl;
        }
        carry += btot;
        __syncthreads();
    }
    if (tid == 0) offs[N] = carry;
}

// ---------------- CSR fill via atomic cursors ----------------
__global__ void k_fill(const int* __restrict__ src, const int* __restrict__ dst,
                       const float* __restrict__ dinv, int* __restrict__ cursor,
                       int* __restrict__ csr_src, float* __restrict__ csr_w, int E) {
    int e = blockIdx.x * blockDim.x + threadIdx.x;
    if (e < E) {
        int s = src[e], d = dst[e];
        int pos = atomicAdd(&cursor[d], 1);
        csr_src[pos] = s;
        csr_w[pos] = dinv[s] * dinv[d];
    }
}

// ---------------- h0 = x @ W^T + b ----------------
// W staged in LDS with rotation swizzle: element (o,k) at [o*128 + ((k+o)&127)]
// -> conflict-free staging writes AND conflict-free per-k column reads.
__global__ __launch_bounds__(256) void k_gemm(const float* __restrict__ x,
                                              const float* __restrict__ W,
                                              const float* __restrict__ b,
                                              float* __restrict__ h, int N) {
    __shared__ float Wsw[HIDDEN_C * HIDDEN_C];  // 64 KiB
    int tid = threadIdx.x;
    for (int i = tid; i < HIDDEN_C * HIDDEN_C; i += 256) {
        int o = i >> 7;
        int k = i & 127;
        Wsw[(o << 7) | ((k + o) & 127)] = W[i];
    }
    __syncthreads();

    int lane = tid & 63;
    int wid = tid >> 6;
    int gw = blockIdx.x * 4 + wid;   // global wave id
    int n0 = gw * 4;                 // 4 nodes per wave
    if (n0 >= N) return;

    float b0 = b[lane];
    float b1 = b[lane + 64];
    float acc[4][2];
#pragma unroll
    for (int i = 0; i < 4; ++i) { acc[i][0] = 0.f; acc[i][1] = 0.f; }

    const float4* x4 = (const float4*)x;
    const float4* xr0 = x4 + (size_t)(n0 + 0) * 32;
    const float4* xr1 = x4 + (size_t)(n0 + 1) * 32;
    const float4* xr2 = x4 + (size_t)(n0 + 2) * 32;
    const float4* xr3 = x4 + (size_t)(n0 + 3) * 32;

    int o1 = lane + 64;
    for (int k4 = 0; k4 < 32; ++k4) {
        float xa[4], xb[4], xc[4], xd[4];
        *(float4*)xa = xr0[k4];
        *(float4*)xb = xr1[k4];
        *(float4*)xc = xr2[k4];
        *(float4*)xd = xr3[k4];
#pragma unroll
        for (int j = 0; j < 4; ++j) {
            int k = k4 * 4 + j;
            float w0 = Wsw[(lane << 7) | ((k + lane) & 127)];
            float w1 = Wsw[(o1 << 7) | ((k + o1) & 127)];
            acc[0][0] += xa[j] * w0; acc[0][1] += xa[j] * w1;
            acc[1][0] += xb[j] * w0; acc[1][1] += xb[j] * w1;
            acc[2][0] += xc[j] * w0; acc[2][1] += xc[j] * w1;
            acc[3][0] += xd[j] * w0; acc[3][1] += xd[j] * w1;
        }
    }
#pragma unroll
    for (int i = 0; i < 4; ++i) {
        size_t n = (size_t)(n0 + i);
        h[n * 128 + lane] = acc[i][0] + b0;
        h[n * 128 + 64 + lane] = acc[i][1] + b1;
    }
}

// ---------------- one APPNP hop: hout = 0.9 * (A_hat hin) + 0.1 * h0 -------
// one wave per node; lane holds float2 (features 2*lane, 2*lane+1)
__global__ __launch_bounds__(256) void k_prop(const float* __restrict__ hin,
                                              const float* __restrict__ h0,
                                              float* __restrict__ hout,
                                              const int* __restrict__ offs,
                                              const int* __restrict__ csr_src,
                                              const float* __restrict__ csr_w,
                                              const float* __restrict__ dinv, int N) {
    int tid = threadIdx.x;
    int lane = tid & 63;
    int wid = tid >> 6;
    int node = blockIdx.x * 4 + wid;
    if (node >= N) return;

    int beg = offs[node];
    int end = offs[node + 1];
    const float2* hin2 = (const float2*)hin;

    float ax = 0.f, ay = 0.f;
    for (int j = beg; j < end; ++j) {
        int s = csr_src[j];
        float w = csr_w[j];
        float2 hv = hin2[(size_t)s * 64 + lane];
        ax += w * hv.x;
        ay += w * hv.y;
    }
    // self-loop
    float dv = dinv[node];
    float ws = dv * dv;
    float2 hs = hin2[(size_t)node * 64 + lane];
    ax += ws * hs.x;
    ay += ws * hs.y;

    float2 h0v = ((const float2*)h0)[(size_t)node * 64 + lane];
    float2 o;
    o.x = (1.0f - ALPHA_C) * ax + ALPHA_C * h0v.x;
    o.y = (1.0f - ALPHA_C) * ay + ALPHA_C * h0v.y;
    ((float2*)hout)[(size_t)node * 64 + lane] = o;
}

extern "C" void kernel_launch(void* const* d_in, const int* in_sizes, int n_in,
                              void* d_out, int out_size, void* d_ws, size_t ws_size,
                              hipStream_t stream) {
    const float* x = (const float*)d_in[0];
    const int* edge = (const int*)d_in[1];  // [2, E] row-major: [0]=src, [1]=dst
    const float* W = (const float*)d_in[2];
    const float* b = (const float*)d_in[3];
    float* out = (float*)d_out;

    const int N = N_NODES_C;
    const int E = N_EDGES_C;
    const int* src = edge;
    const int* dst = edge + E;

    // workspace carve-up (512 B aligned)
    char* ws = (char*)d_ws;
    size_t off = 0;
    auto carve = [&](size_t bytes) -> void* {
        void* p = ws + off;
        off = (off + bytes + 511) & ~(size_t)511;
        return p;
    };
    float* h0      = (float*)carve((size_t)N * HIDDEN_C * sizeof(float));  // 51.2 MB
    float* hA      = (float*)carve((size_t)N * HIDDEN_C * sizeof(float));  // 51.2 MB
    int*   deg     = (int*)  carve((size_t)N * sizeof(int));
    float* dinv    = (float*)carve((size_t)N * sizeof(float));
    int*   offs    = (int*)  carve((size_t)(N + 1) * sizeof(int));
    int*   cursor  = (int*)  carve((size_t)N * sizeof(int));
    int*   csr_src = (int*)  carve((size_t)E * sizeof(int));
    float* csr_w   = (float*)carve((size_t)E * sizeof(float));
    (void)ws_size;

    hipMemsetAsync(deg, 0, (size_t)N * sizeof(int), stream);

    int eb = (E + 255) / 256;
    k_deg<<<eb, 256, 0, stream>>>(dst, deg, E);
    k_scan<<<1, 1024, 0, stream>>>(deg, offs, cursor, dinv, N);
    k_fill<<<eb, 256, 0, stream>>>(src, dst, dinv, cursor, csr_src, csr_w, E);

    k_gemm<<<(N + 15) / 16, 256, 0, stream>>>(x, W, b, h0, N);

    // 10 hops, ping-pong hA <-> out; final (10th) hop writes d_out
    const float* hin = h0;
    for (int k = 0; k < K_HOPS_C; ++k) {
        float* hout = ((k & 1) == 0) ? hA : out;
        k_prop<<<(N + 3) / 4, 256, 0, stream>>>(hin, h0, hout, offs, csr_src, csr_w, dinv, N);
        hin = hout;
    }
}

// Round 2
// 964.311 us; speedup vs baseline: 1.3488x; 1.3488x over previous
//
#include <hip/hip_runtime.h>

#define N_NODES_C 100000
#define N_EDGES_C 600000
#define HIDDEN_C 128
#define K_HOPS_C 10

// ---- bf16 helpers (round-to-nearest-even pack, truncating unpack) ----
__device__ __forceinline__ unsigned short f2bf(float f) {
    unsigned u = __float_as_uint(f);
    return (unsigned short)((u + 0x7FFFu + ((u >> 16) & 1u)) >> 16);
}
__device__ __forceinline__ float bf_lo(unsigned p) {
    return __uint_as_float(p << 16);
}
__device__ __forceinline__ float bf_hi(unsigned p) {
    return __uint_as_float(p & 0xFFFF0000u);
}

// ---------------- degree count (in-degree over real edges) ----------------
__global__ void k_deg(const int* __restrict__ dst, int* __restrict__ deg, int E) {
    int e = blockIdx.x * blockDim.x + threadIdx.x;
    if (e < E) atomicAdd(&deg[dst[e]], 1);
}

// ------- single-block scan: offs = exclusive scan(deg); cursor = copy; -----
// ------- dinv[i] = rsqrt(deg[i] + 1)  (+1 = self-loop)                 -----
__global__ __launch_bounds__(1024) void k_scan(const int* __restrict__ deg,
                                               int* __restrict__ offs,
                                               int* __restrict__ cursor,
                                               float* __restrict__ dinv, int N) {
    __shared__ int wtot[16];
    int tid = threadIdx.x;
    int lane = tid & 63;
    int wid = tid >> 6;
    int carry = 0;
    for (int base = 0; base < N; base += 1024) {
        int i = base + tid;
        int v = (i < N) ? deg[i] : 0;
        if (i < N) dinv[i] = rsqrtf((float)(v + 1));
        int incl = v;
#pragma unroll
        for (int d = 1; d < 64; d <<= 1) {
            int t = __shfl_up(incl, (unsigned)d, 64);
            if (lane >= d) incl += t;
        }
        if (lane == 63) wtot[wid] = incl;
        __syncthreads();
        int woff = 0, btot = 0;
#pragma unroll
        for (int w = 0; w < 16; ++w) {
            int t = wtot[w];
            if (w < wid) woff += t;
            btot += t;
        }
        int excl = woff + incl - v;
        if (i < N) {
            offs[i] = carry + excl;
            cursor[i] = carry + excl;
        }
        carry += btot;
        __syncthreads();
    }
    if (tid == 0) offs[N] = carry;
}

// ---------------- CSR fill via atomic cursors ----------------
__global__ void k_fill(const int* __restrict__ src, const int* __restrict__ dst,
                       const float* __restrict__ dinv, int* __restrict__ cursor,
                       int* __restrict__ csr_src, float* __restrict__ csr_w, int E) {
    int e = blockIdx.x * blockDim.x + threadIdx.x;
    if (e < E) {
        int s = src[e], d = dst[e];
        int pos = atomicAdd(&cursor[d], 1);
        csr_src[pos] = s;
        csr_w[pos] = dinv[s] * dinv[d];
    }
}

// ---------------- h0 = x @ W^T + b  (fp32 out + bf16 shadow) ----------------
// W staged in LDS with rotation swizzle: element (o,k) at [o*128 + ((k+o)&127)]
// -> conflict-free staging writes AND 2-way(free) per-k column reads.
// 8 nodes per wave for ILP: 16 FMAs per LDS-read pair, 8 x-row loads in flight.
__global__ __launch_bounds__(256) void k_gemm(const float* __restrict__ x,
                                              const float* __restrict__ W,
                                              const float* __restrict__ b,
                                              float* __restrict__ h,
                                              unsigned short* __restrict__ hb, int N) {
    __shared__ float Wsw[HIDDEN_C * HIDDEN_C];  // 64 KiB
    int tid = threadIdx.x;
    for (int i = tid; i < HIDDEN_C * HIDDEN_C; i += 256) {
        int o = i >> 7;
        int k = i & 127;
        Wsw[(o << 7) | ((k + o) & 127)] = W[i];
    }
    __syncthreads();

    int lane = tid & 63;
    int wid = tid >> 6;
    int gw = blockIdx.x * 4 + wid;   // global wave id
    int n0 = gw * 8;                 // 8 nodes per wave
    if (n0 >= N) return;

    float b0 = b[lane];
    float b1 = b[lane + 64];
    float acc[8][2];
#pragma unroll
    for (int i = 0; i < 8; ++i) { acc[i][0] = 0.f; acc[i][1] = 0.f; }

    const float4* xr[8];
#pragma unroll
    for (int i = 0; i < 8; ++i)
        xr[i] = (const float4*)x + (size_t)(n0 + i) * 32;

    int o1 = lane + 64;
    for (int k4 = 0; k4 < 32; ++k4) {
        float4 xv[8];
#pragma unroll
        for (int i = 0; i < 8; ++i) xv[i] = xr[i][k4];
#pragma unroll
        for (int j = 0; j < 4; ++j) {
            int k = (k4 << 2) + j;
            float w0 = Wsw[(lane << 7) | ((k + lane) & 127)];
            float w1 = Wsw[(o1 << 7) | ((k + o1) & 127)];
#pragma unroll
            for (int i = 0; i < 8; ++i) {
                float xij = ((const float*)&xv[i])[j];
                acc[i][0] += xij * w0;
                acc[i][1] += xij * w1;
            }
        }
    }
#pragma unroll
    for (int i = 0; i < 8; ++i) {
        size_t n = (size_t)(n0 + i);
        if (n0 + i < N) {
            float v0 = acc[i][0] + b0;
            float v1 = acc[i][1] + b1;
            h[n * 128 + lane] = v0;
            h[n * 128 + 64 + lane] = v1;
            hb[n * 128 + lane] = f2bf(v0);
            hb[n * 128 + 64 + lane] = f2bf(v1);
        }
    }
}

// ---- one APPNP hop: hout = 0.9*(A_hat hin) + 0.1*h0 -----------------------
// hin is bf16 (packed 2/lane); accumulate fp32; write bf16 (mid) or fp32 (final)
__global__ __launch_bounds__(256) void k_prop(const unsigned* __restrict__ hin2,
                                              const float* __restrict__ h0,
                                              unsigned* __restrict__ hout_b,
                                              float* __restrict__ hout_f,
                                              const int* __restrict__ offs,
                                              const int* __restrict__ csr_src,
                                              const float* __restrict__ csr_w,
                                              const float* __restrict__ dinv,
                                              int N, int final_hop) {
    int tid = threadIdx.x;
    int lane = tid & 63;
    int wid = tid >> 6;
    int node = blockIdx.x * 4 + wid;
    if (node >= N) return;

    int beg = offs[node];
    int end = offs[node + 1];

    float ax = 0.f, ay = 0.f;
    int j = beg;
    for (; j + 2 <= end; j += 2) {
        int s0 = csr_src[j];
        int s1 = csr_src[j + 1];
        float w0 = csr_w[j];
        float w1 = csr_w[j + 1];
        unsigned p0 = hin2[(size_t)s0 * 64 + lane];
        unsigned p1 = hin2[(size_t)s1 * 64 + lane];
        ax += w0 * bf_lo(p0);
        ay += w0 * bf_hi(p0);
        ax += w1 * bf_lo(p1);
        ay += w1 * bf_hi(p1);
    }
    if (j < end) {
        int s = csr_src[j];
        float w = csr_w[j];
        unsigned p = hin2[(size_t)s * 64 + lane];
        ax += w * bf_lo(p);
        ay += w * bf_hi(p);
    }
    // self-loop
    float dv = dinv[node];
    float ws = dv * dv;
    unsigned ps = hin2[(size_t)node * 64 + lane];
    ax += ws * bf_lo(ps);
    ay += ws * bf_hi(ps);

    float2 h0v = ((const float2*)h0)[(size_t)node * 64 + lane];
    float ox = 0.9f * ax + 0.1f * h0v.x;
    float oy = 0.9f * ay + 0.1f * h0v.y;

    if (final_hop) {
        float2 o; o.x = ox; o.y = oy;
        ((float2*)hout_f)[(size_t)node * 64 + lane] = o;
    } else {
        unsigned p = (unsigned)f2bf(ox) | ((unsigned)f2bf(oy) << 16);
        hout_b[(size_t)node * 64 + lane] = p;
    }
}

extern "C" void kernel_launch(void* const* d_in, const int* in_sizes, int n_in,
                              void* d_out, int out_size, void* d_ws, size_t ws_size,
                              hipStream_t stream) {
    const float* x = (const float*)d_in[0];
    const int* edge = (const int*)d_in[1];  // [2, E] row-major: [0]=src, [1]=dst
    const float* W = (const float*)d_in[2];
    const float* b = (const float*)d_in[3];
    float* out = (float*)d_out;

    const int N = N_NODES_C;
    const int E = N_EDGES_C;
    const int* src = edge;
    const int* dst = edge + E;

    // workspace carve-up (512 B aligned).  fp32 h0 lives in d_out.
    char* ws = (char*)d_ws;
    size_t off = 0;
    auto carve = [&](size_t bytes) -> void* {
        void* p = ws + off;
        off = (off + bytes + 511) & ~(size_t)511;
        return p;
    };
    unsigned short* h0b = (unsigned short*)carve((size_t)N * HIDDEN_C * 2);  // 25.6 MB
    unsigned short* bA  = (unsigned short*)carve((size_t)N * HIDDEN_C * 2);  // 25.6 MB
    unsigned short* bB  = (unsigned short*)carve((size_t)N * HIDDEN_C * 2);  // 25.6 MB
    int*   deg     = (int*)  carve((size_t)N * sizeof(int));
    float* dinv    = (float*)carve((size_t)N * sizeof(float));
    int*   offs    = (int*)  carve((size_t)(N + 1) * sizeof(int));
    int*   cursor  = (int*)  carve((size_t)N * sizeof(int));
    int*   csr_src = (int*)  carve((size_t)E * sizeof(int));
    float* csr_w   = (float*)carve((size_t)E * sizeof(float));
    (void)ws_size;

    float* h0f = out;  // fp32 h0 hosted in d_out (final hop overwrites in-place, per-thread safe)

    hipMemsetAsync(deg, 0, (size_t)N * sizeof(int), stream);

    int eb = (E + 255) / 256;
    k_deg<<<eb, 256, 0, stream>>>(dst, deg, E);
    k_scan<<<1, 1024, 0, stream>>>(deg, offs, cursor, dinv, N);
    k_fill<<<eb, 256, 0, stream>>>(src, dst, dinv, cursor, csr_src, csr_w, E);

    k_gemm<<<(N + 31) / 32, 256, 0, stream>>>(x, W, b, h0f, h0b, N);

    // 10 hops: hops 1..9 write bf16 ping-pong, hop 10 writes fp32 d_out
    const unsigned* hin = (const unsigned*)h0b;
    for (int k = 0; k < K_HOPS_C; ++k) {
        int fin = (k == K_HOPS_C - 1);
        unsigned* houtb = ((k & 1) == 0) ? (unsigned*)bA : (unsigned*)bB;
        k_prop<<<(N + 3) / 4, 256, 0, stream>>>(hin, h0f, fin ? nullptr : houtb,
                                                fin ? out : nullptr,
                                                offs, csr_src, csr_w, dinv, N, fin);
        hin = houtb;
    }
}

// Round 3
// 731.278 us; speedup vs baseline: 1.7786x; 1.3187x over previous
//
#include <hip/hip_runtime.h>

#define N_NODES_C 100000
#define N_EDGES_C 600000
#define HIDDEN_C 128
#define K_HOPS_C 10

typedef short short8 __attribute__((ext_vector_type(8)));   // 8 bf16 (4 VGPRs)
typedef float f32x16 __attribute__((ext_vector_type(16)));  // 32x32 accumulator

// ---- bf16 helpers (round-to-nearest-even pack, exact unpack) ----
__device__ __forceinline__ unsigned short f2bf(float f) {
    unsigned u = __float_as_uint(f);
    return (unsigned short)((u + 0x7FFFu + ((u >> 16) & 1u)) >> 16);
}
__device__ __forceinline__ float bf_lo(unsigned p) { return __uint_as_float(p << 16); }
__device__ __forceinline__ float bf_hi(unsigned p) { return __uint_as_float(p & 0xFFFF0000u); }

// ---------------- degree count (in-degree over real edges) ----------------
__global__ void k_deg(const int* __restrict__ dst, int* __restrict__ deg, int E) {
    int e = blockIdx.x * blockDim.x + threadIdx.x;
    if (e < E) atomicAdd(&deg[dst[e]], 1);
}

// ------- single-block scan: offs = exclusive scan(deg); cursor = copy; -----
__global__ __launch_bounds__(1024) void k_scan(const int* __restrict__ deg,
                                               int* __restrict__ offs,
                                               int* __restrict__ cursor,
                                               float* __restrict__ dinv, int N) {
    __shared__ int wtot[16];
    int tid = threadIdx.x;
    int lane = tid & 63;
    int wid = tid >> 6;
    int carry = 0;
    for (int base = 0; base < N; base += 1024) {
        int i = base + tid;
        int v = (i < N) ? deg[i] : 0;
        if (i < N) dinv[i] = rsqrtf((float)(v + 1));
        int incl = v;
#pragma unroll
        for (int d = 1; d < 64; d <<= 1) {
            int t = __shfl_up(incl, (unsigned)d, 64);
            if (lane >= d) incl += t;
        }
        if (lane == 63) wtot[wid] = incl;
        __syncthreads();
        int woff = 0, btot = 0;
#pragma unroll
        for (int w = 0; w < 16; ++w) {
            int t = wtot[w];
            if (w < wid) woff += t;
            btot += t;
        }
        int excl = woff + incl - v;
        if (i < N) {
            offs[i] = carry + excl;
            cursor[i] = carry + excl;
        }
        carry += btot;
        __syncthreads();
    }
    if (tid == 0) offs[N] = carry;
}

// ---------------- CSR fill via atomic cursors (fused src+weight) ----------
__global__ void k_fill(const int* __restrict__ src, const int* __restrict__ dst,
                       const float* __restrict__ dinv, int* __restrict__ cursor,
                       uint2* __restrict__ csr, int E) {
    int e = blockIdx.x * blockDim.x + threadIdx.x;
    if (e < E) {
        int s = src[e], d = dst[e];
        int pos = atomicAdd(&cursor[d], 1);
        uint2 v;
        v.x = (unsigned)s;
        v.y = __float_as_uint(dinv[s] * dinv[d]);
        csr[pos] = v;
    }
}

// ---------------- h0b = bf16(x @ W^T + b) via 32x32x16 bf16 MFMA -----------
// W in LDS as bf16, XOR-swizzled 16B groups: row o, group g at Wb[o*128 + (g^(o&15))*8]
// -> staging writes and fragment reads both <=2-way banked (free).
// A-fragments loaded straight from global (x rows have no cross-wave reuse).
__global__ __launch_bounds__(256) void k_gemm(const float* __restrict__ x,
                                              const float* __restrict__ W,
                                              const float* __restrict__ b,
                                              unsigned short* __restrict__ hb, int N) {
    __shared__ unsigned short Wb[HIDDEN_C * HIDDEN_C];  // 32 KiB bf16
    int tid = threadIdx.x;
    // stage W: 2048 chunks of 8 floats -> 8 bf16 (16 B)
#pragma unroll
    for (int i = 0; i < 8; ++i) {
        int c = tid + 256 * i;      // 0..2047
        int m = c >> 4;             // W row (output o)
        int g = c & 15;             // 8-element group within row
        const float4* wsrc = (const float4*)W + m * 32 + g * 2;
        float4 wa = wsrc[0];
        float4 wb = wsrc[1];
        unsigned short t8[8];
        t8[0] = f2bf(wa.x); t8[1] = f2bf(wa.y); t8[2] = f2bf(wa.z); t8[3] = f2bf(wa.w);
        t8[4] = f2bf(wb.x); t8[5] = f2bf(wb.y); t8[6] = f2bf(wb.z); t8[7] = f2bf(wb.w);
        int gs = g ^ (m & 15);
        *(uint4*)&Wb[m * 128 + gs * 8] = *(const uint4*)t8;
    }
    __syncthreads();

    int lane = tid & 63;
    int wv = tid >> 6;
    int row0 = blockIdx.x * 128 + wv * 32;  // this wave's 32-row slab
    int m = lane & 31;
    int half = lane >> 5;

    int row = row0 + m;
    if (row >= N) row = N - 1;  // clamp; epilogue guards writes
    const float4* xrow = (const float4*)(x + (size_t)row * 128);

    f32x16 acc[4];
#pragma unroll
    for (int t = 0; t < 4; ++t)
#pragma unroll
        for (int r = 0; r < 16; ++r) acc[t][r] = 0.f;

    for (int s = 0; s < 8; ++s) {
        // A frag: x[row][16s + 8*half + (0..7)]
        int kb = s * 16 + half * 8;
        float4 x0 = xrow[kb >> 2];
        float4 x1 = xrow[(kb >> 2) + 1];
        union { unsigned short u[8]; short8 v; } af;
        af.u[0] = f2bf(x0.x); af.u[1] = f2bf(x0.y); af.u[2] = f2bf(x0.z); af.u[3] = f2bf(x0.w);
        af.u[4] = f2bf(x1.x); af.u[5] = f2bf(x1.y); af.u[6] = f2bf(x1.z); af.u[7] = f2bf(x1.w);
        int g = kb >> 3;  // = 2s + half
#pragma unroll
        for (int t = 0; t < 4; ++t) {
            int r = t * 32 + m;  // W row = output col
            short8 bfrag = *(const short8*)&Wb[r * 128 + ((g ^ (r & 15)) << 3)];
            acc[t] = __builtin_amdgcn_mfma_f32_32x32x16_bf16(af.v, bfrag, acc[t], 0, 0, 0);
        }
    }

    // epilogue: D[row=(reg&3)+8*(reg>>2)+4*half][col=lane&31]
    float bias[4];
#pragma unroll
    for (int t = 0; t < 4; ++t) bias[t] = b[t * 32 + m];
#pragma unroll
    for (int t = 0; t < 4; ++t) {
#pragma unroll
        for (int r = 0; r < 16; ++r) {
            int rrow = (r & 3) + 8 * (r >> 2) + 4 * half;
            int node = row0 + rrow;
            if (node < N) {
                float v = acc[t][r] + bias[t];
                hb[(size_t)node * 128 + t * 32 + m] = f2bf(v);
            }
        }
    }
}

// ---- one APPNP hop: hout = 0.9*(A_hat hin) + 0.1*h0  (all-bf16 state) -----
__global__ __launch_bounds__(256) void k_prop(const unsigned* __restrict__ hin2,
                                              const unsigned* __restrict__ h0b2,
                                              unsigned* __restrict__ hout_b,
                                              float* __restrict__ hout_f,
                                              const int* __restrict__ offs,
                                              const uint2* __restrict__ csr,
                                              const float* __restrict__ dinv,
                                              int N, int final_hop) {
    int tid = threadIdx.x;
    int lane = tid & 63;
    int wid = tid >> 6;
    int node = blockIdx.x * 4 + wid;
    if (node >= N) return;

    int beg = offs[node];
    int end = offs[node + 1];

    float ax = 0.f, ay = 0.f;
    int j = beg;
    for (; j + 4 <= end; j += 4) {
        uint2 e0 = csr[j];
        uint2 e1 = csr[j + 1];
        uint2 e2 = csr[j + 2];
        uint2 e3 = csr[j + 3];
        unsigned p0 = hin2[(e0.x << 6) + lane];
        unsigned p1 = hin2[(e1.x << 6) + lane];
        unsigned p2 = hin2[(e2.x << 6) + lane];
        unsigned p3 = hin2[(e3.x << 6) + lane];
        float w0 = __uint_as_float(e0.y), w1 = __uint_as_float(e1.y);
        float w2 = __uint_as_float(e2.y), w3 = __uint_as_float(e3.y);
        ax += w0 * bf_lo(p0); ay += w0 * bf_hi(p0);
        ax += w1 * bf_lo(p1); ay += w1 * bf_hi(p1);
        ax += w2 * bf_lo(p2); ay += w2 * bf_hi(p2);
        ax += w3 * bf_lo(p3); ay += w3 * bf_hi(p3);
    }
    for (; j < end; ++j) {
        uint2 e = csr[j];
        unsigned p = hin2[(e.x << 6) + lane];
        float w = __uint_as_float(e.y);
        ax += w * bf_lo(p); ay += w * bf_hi(p);
    }
    // self-loop
    float dv = dinv[node];
    float ws = dv * dv;
    unsigned ps = hin2[((unsigned)node << 6) + lane];
    ax += ws * bf_lo(ps);
    ay += ws * bf_hi(ps);

    unsigned q = h0b2[((unsigned)node << 6) + lane];
    float ox = 0.9f * ax + 0.1f * bf_lo(q);
    float oy = 0.9f * ay + 0.1f * bf_hi(q);

    if (final_hop) {
        float2 o; o.x = ox; o.y = oy;
        ((float2*)hout_f)[((size_t)node << 6) + lane] = o;
    } else {
        unsigned p = (unsigned)f2bf(ox) | ((unsigned)f2bf(oy) << 16);
        hout_b[((unsigned)node << 6) + lane] = p;
    }
}

extern "C" void kernel_launch(void* const* d_in, const int* in_sizes, int n_in,
                              void* d_out, int out_size, void* d_ws, size_t ws_size,
                              hipStream_t stream) {
    const float* x = (const float*)d_in[0];
    const int* edge = (const int*)d_in[1];  // [2, E] row-major: [0]=src, [1]=dst
    const float* W = (const float*)d_in[2];
    const float* b = (const float*)d_in[3];
    float* out = (float*)d_out;

    const int N = N_NODES_C;
    const int E = N_EDGES_C;
    const int* src = edge;
    const int* dst = edge + E;

    char* ws = (char*)d_ws;
    size_t off = 0;
    auto carve = [&](size_t bytes) -> void* {
        void* p = ws + off;
        off = (off + bytes + 511) & ~(size_t)511;
        return p;
    };
    unsigned short* h0b = (unsigned short*)carve((size_t)N * HIDDEN_C * 2);  // 25.6 MB
    unsigned short* bA  = (unsigned short*)carve((size_t)N * HIDDEN_C * 2);  // 25.6 MB
    unsigned short* bB  = (unsigned short*)carve((size_t)N * HIDDEN_C * 2);  // 25.6 MB
    int*   deg     = (int*)  carve((size_t)N * sizeof(int));
    float* dinv    = (float*)carve((size_t)N * sizeof(float));
    int*   offs    = (int*)  carve((size_t)(N + 1) * sizeof(int));
    int*   cursor  = (int*)  carve((size_t)N * sizeof(int));
    uint2* csr     = (uint2*)carve((size_t)E * sizeof(uint2));
    (void)ws_size;

    hipMemsetAsync(deg, 0, (size_t)N * sizeof(int), stream);

    int eb = (E + 255) / 256;
    k_deg<<<eb, 256, 0, stream>>>(dst, deg, E);
    k_scan<<<1, 1024, 0, stream>>>(deg, offs, cursor, dinv, N);
    k_fill<<<eb, 256, 0, stream>>>(src, dst, dinv, cursor, csr, E);

    k_gemm<<<(N + 127) / 128, 256, 0, stream>>>(x, W, b, h0b, N);

    // 10 hops: hops 1..9 write bf16 ping-pong, hop 10 writes fp32 d_out
    const unsigned* hin = (const unsigned*)h0b;
    for (int k = 0; k < K_HOPS_C; ++k) {
        int fin = (k == K_HOPS_C - 1);
        unsigned* houtb = ((k & 1) == 0) ? (unsigned*)bA : (unsigned*)bB;
        k_prop<<<(N + 3) / 4, 256, 0, stream>>>(hin, (const unsigned*)h0b,
                                                fin ? nullptr : houtb,
                                                fin ? out : nullptr,
                                                offs, csr, dinv, N, fin);
        hin = houtb;
    }
}

// Round 4
// 658.397 us; speedup vs baseline: 1.9755x; 1.1107x over previous
//
#include <hip/hip_runtime.h>

#define N_NODES_C 100000
#define N_EDGES_C 600000
#define HIDDEN_C 128
#define K_HOPS_C 10
#define SCAN_B 98  // ceil(100000/1024)

typedef short short8 __attribute__((ext_vector_type(8)));   // 8 bf16 (4 VGPRs)
typedef float f32x16 __attribute__((ext_vector_type(16)));  // 32x32 accumulator

// ---- bf16 helpers (round-to-nearest-even pack, exact unpack) ----
__device__ __forceinline__ unsigned short f2bf(float f) {
    unsigned u = __float_as_uint(f);
    return (unsigned short)((u + 0x7FFFu + ((u >> 16) & 1u)) >> 16);
}
__device__ __forceinline__ float bf_lo(unsigned p) { return __uint_as_float(p << 16); }
__device__ __forceinline__ float bf_hi(unsigned p) { return __uint_as_float(p & 0xFFFF0000u); }

// ---------------- degree count (in-degree over real edges) ----------------
__global__ void k_deg(const int* __restrict__ dst, int* __restrict__ deg, int E) {
    int e = blockIdx.x * blockDim.x + threadIdx.x;
    if (e < E) atomicAdd(&deg[dst[e]], 1);
}

// ---------------- multi-block exclusive scan, phase A ----------------------
// block-local exclusive scan of deg -> offs (local), block total -> blksum
__global__ __launch_bounds__(1024) void k_scan_a(const int* __restrict__ deg,
                                                 int* __restrict__ offs,
                                                 int* __restrict__ blksum,
                                                 float* __restrict__ dinv, int N) {
    __shared__ int wtot[16];
    int tid = threadIdx.x;
    int i = blockIdx.x * 1024 + tid;
    int lane = tid & 63;
    int wid = tid >> 6;
    int v = (i < N) ? deg[i] : 0;
    if (i < N) dinv[i] = rsqrtf((float)(v + 1));
    int incl = v;
#pragma unroll
    for (int d = 1; d < 64; d <<= 1) {
        int t = __shfl_up(incl, (unsigned)d, 64);
        if (lane >= d) incl += t;
    }
    if (lane == 63) wtot[wid] = incl;
    __syncthreads();
    int woff = 0, btot = 0;
#pragma unroll
    for (int w = 0; w < 16; ++w) {
        int t = wtot[w];
        if (w < wid) woff += t;
        btot += t;
    }
    if (i < N) offs[i] = woff + incl - v;
    if (tid == 0) blksum[blockIdx.x] = btot;
}

// ---------------- phase B: scan the 98 block sums (1 tiny block) -----------
__global__ __launch_bounds__(128) void k_scan_b(const int* __restrict__ blksum,
                                                int* __restrict__ blkoff,
                                                int* __restrict__ offs, int NB, int N) {
    __shared__ int wt[2];
    int t = threadIdx.x;
    int lane = t & 63;
    int w = t >> 6;
    int v = (t < NB) ? blksum[t] : 0;
    int incl = v;
#pragma unroll
    for (int d = 1; d < 64; d <<= 1) {
        int s = __shfl_up(incl, (unsigned)d, 64);
        if (lane >= d) incl += s;
    }
    if (lane == 63) wt[w] = incl;
    __syncthreads();
    int excl = incl - v + (w == 1 ? wt[0] : 0);
    if (t < NB) blkoff[t] = excl;
    if (t == 127) offs[N] = wt[0] + wt[1];
}

// ---------------- phase C: add block offsets, emit cursor ------------------
__global__ __launch_bounds__(1024) void k_scan_c(int* __restrict__ offs,
                                                 int* __restrict__ cursor,
                                                 const int* __restrict__ blkoff, int N) {
    int i = blockIdx.x * 1024 + threadIdx.x;
    if (i < N) {
        int v = offs[i] + blkoff[blockIdx.x];
        offs[i] = v;
        cursor[i] = v;
    }
}

// ---------------- CSR fill via atomic cursors (fused src+weight) ----------
__global__ void k_fill(const int* __restrict__ src, const int* __restrict__ dst,
                       const float* __restrict__ dinv, int* __restrict__ cursor,
                       uint2* __restrict__ csr, int E) {
    int e = blockIdx.x * blockDim.x + threadIdx.x;
    if (e < E) {
        int s = src[e], d = dst[e];
        int pos = atomicAdd(&cursor[d], 1);
        uint2 v;
        v.x = (unsigned)s;
        v.y = __float_as_uint(dinv[s] * dinv[d]);
        csr[pos] = v;
    }
}

// ---------------- h0b = bf16(x @ W^T + b) via 32x32x16 bf16 MFMA -----------
__global__ __launch_bounds__(256) void k_gemm(const float* __restrict__ x,
                                              const float* __restrict__ W,
                                              const float* __restrict__ b,
                                              unsigned short* __restrict__ hb, int N) {
    __shared__ unsigned short Wb[HIDDEN_C * HIDDEN_C];  // 32 KiB bf16
    int tid = threadIdx.x;
#pragma unroll
    for (int i = 0; i < 8; ++i) {
        int c = tid + 256 * i;      // 0..2047
        int m = c >> 4;             // W row (output o)
        int g = c & 15;             // 8-element group within row
        const float4* wsrc = (const float4*)W + m * 32 + g * 2;
        float4 wa = wsrc[0];
        float4 wb = wsrc[1];
        unsigned short t8[8];
        t8[0] = f2bf(wa.x); t8[1] = f2bf(wa.y); t8[2] = f2bf(wa.z); t8[3] = f2bf(wa.w);
        t8[4] = f2bf(wb.x); t8[5] = f2bf(wb.y); t8[6] = f2bf(wb.z); t8[7] = f2bf(wb.w);
        int gs = g ^ (m & 15);
        *(uint4*)&Wb[m * 128 + gs * 8] = *(const uint4*)t8;
    }
    __syncthreads();

    int lane = tid & 63;
    int wv = tid >> 6;
    int row0 = blockIdx.x * 128 + wv * 32;
    int m = lane & 31;
    int half = lane >> 5;

    int row = row0 + m;
    if (row >= N) row = N - 1;
    const float4* xrow = (const float4*)(x + (size_t)row * 128);

    f32x16 acc[4];
#pragma unroll
    for (int t = 0; t < 4; ++t)
#pragma unroll
        for (int r = 0; r < 16; ++r) acc[t][r] = 0.f;

    for (int s = 0; s < 8; ++s) {
        int kb = s * 16 + half * 8;
        float4 x0 = xrow[kb >> 2];
        float4 x1 = xrow[(kb >> 2) + 1];
        union { unsigned short u[8]; short8 v; } af;
        af.u[0] = f2bf(x0.x); af.u[1] = f2bf(x0.y); af.u[2] = f2bf(x0.z); af.u[3] = f2bf(x0.w);
        af.u[4] = f2bf(x1.x); af.u[5] = f2bf(x1.y); af.u[6] = f2bf(x1.z); af.u[7] = f2bf(x1.w);
        int g = kb >> 3;
#pragma unroll
        for (int t = 0; t < 4; ++t) {
            int r = t * 32 + m;
            short8 bfrag = *(const short8*)&Wb[r * 128 + ((g ^ (r & 15)) << 3)];
            acc[t] = __builtin_amdgcn_mfma_f32_32x32x16_bf16(af.v, bfrag, acc[t], 0, 0, 0);
        }
    }

    float bias[4];
#pragma unroll
    for (int t = 0; t < 4; ++t) bias[t] = b[t * 32 + m];
#pragma unroll
    for (int t = 0; t < 4; ++t) {
#pragma unroll
        for (int r = 0; r < 16; ++r) {
            int rrow = (r & 3) + 8 * (r >> 2) + 4 * half;
            int node = row0 + rrow;
            if (node < N) {
                float v = acc[t][r] + bias[t];
                hb[(size_t)node * 128 + t * 32 + m] = f2bf(v);
            }
        }
    }
}

// ---- one APPNP hop: hout = 0.9*(A_hat hin) + 0.1*h0  (all-bf16 state) -----
// Wave = 1 node. Lane L: edge-slot q=L>>4, row-chunk f=L&15.
// One dwordx4 gather instruction fetches 4 edges' 256B rows (16 lanes/row).
__global__ __launch_bounds__(256) void k_prop(const uint4* __restrict__ hin4,
                                              const uint4* __restrict__ h04,
                                              uint4* __restrict__ hout_b,
                                              float* __restrict__ hout_f,
                                              const int* __restrict__ offs,
                                              const uint2* __restrict__ csr,
                                              const float* __restrict__ dinv,
                                              int N, int final_hop) {
    int tid = threadIdx.x;
    int lane = tid & 63;
    int wid = tid >> 6;
    int node = blockIdx.x * 4 + wid;
    if (node >= N) return;

    int q = lane >> 4;   // edge slot 0..3
    int f = lane & 15;   // 16B chunk within row

    int beg = offs[node];
    int end = offs[node + 1];

    float acc[8];
#pragma unroll
    for (int i = 0; i < 8; ++i) acc[i] = 0.f;

    for (int j = beg; j < end; j += 4) {
        int jj = j + q;
        if (jj < end) {
            uint2 e = csr[jj];
            uint4 p = hin4[(size_t)e.x * 16 + f];
            float w = __uint_as_float(e.y);
            acc[0] += w * bf_lo(p.x); acc[1] += w * bf_hi(p.x);
            acc[2] += w * bf_lo(p.y); acc[3] += w * bf_hi(p.y);
            acc[4] += w * bf_lo(p.z); acc[5] += w * bf_hi(p.z);
            acc[6] += w * bf_lo(p.w); acc[7] += w * bf_hi(p.w);
        }
    }
    // self-loop: only slot 0 contributes
    if (q == 0) {
        float dv = dinv[node];
        float ws = dv * dv;
        uint4 p = hin4[(size_t)node * 16 + f];
        acc[0] += ws * bf_lo(p.x); acc[1] += ws * bf_hi(p.x);
        acc[2] += ws * bf_lo(p.y); acc[3] += ws * bf_hi(p.y);
        acc[4] += ws * bf_lo(p.z); acc[5] += ws * bf_hi(p.z);
        acc[6] += ws * bf_lo(p.w); acc[7] += ws * bf_hi(p.w);
    }
    // reduce across the 4 edge slots (lanes ^16, ^32)
#pragma unroll
    for (int i = 0; i < 8; ++i) {
        acc[i] += __shfl_xor(acc[i], 16, 64);
        acc[i] += __shfl_xor(acc[i], 32, 64);
    }

    if (q == 0) {
        uint4 hq = h04[(size_t)node * 16 + f];
        float o[8];
        o[0] = 0.9f * acc[0] + 0.1f * bf_lo(hq.x);
        o[1] = 0.9f * acc[1] + 0.1f * bf_hi(hq.x);
        o[2] = 0.9f * acc[2] + 0.1f * bf_lo(hq.y);
        o[3] = 0.9f * acc[3] + 0.1f * bf_hi(hq.y);
        o[4] = 0.9f * acc[4] + 0.1f * bf_lo(hq.z);
        o[5] = 0.9f * acc[5] + 0.1f * bf_hi(hq.z);
        o[6] = 0.9f * acc[6] + 0.1f * bf_lo(hq.w);
        o[7] = 0.9f * acc[7] + 0.1f * bf_hi(hq.w);
        if (final_hop) {
            float4* dst0 = (float4*)(hout_f + (size_t)node * 128 + f * 8);
            float4 v0; v0.x = o[0]; v0.y = o[1]; v0.z = o[2]; v0.w = o[3];
            float4 v1; v1.x = o[4]; v1.y = o[5]; v1.z = o[6]; v1.w = o[7];
            dst0[0] = v0;
            dst0[1] = v1;
        } else {
            uint4 p;
            p.x = (unsigned)f2bf(o[0]) | ((unsigned)f2bf(o[1]) << 16);
            p.y = (unsigned)f2bf(o[2]) | ((unsigned)f2bf(o[3]) << 16);
            p.z = (unsigned)f2bf(o[4]) | ((unsigned)f2bf(o[5]) << 16);
            p.w = (unsigned)f2bf(o[6]) | ((unsigned)f2bf(o[7]) << 16);
            hout_b[(size_t)node * 16 + f] = p;
        }
    }
}

extern "C" void kernel_launch(void* const* d_in, const int* in_sizes, int n_in,
                              void* d_out, int out_size, void* d_ws, size_t ws_size,
                              hipStream_t stream) {
    const float* x = (const float*)d_in[0];
    const int* edge = (const int*)d_in[1];  // [2, E]: [0]=src, [1]=dst
    const float* W = (const float*)d_in[2];
    const float* b = (const float*)d_in[3];
    float* out = (float*)d_out;

    const int N = N_NODES_C;
    const int E = N_EDGES_C;
    const int* src = edge;
    const int* dst = edge + E;

    char* ws = (char*)d_ws;
    size_t off = 0;
    auto carve = [&](size_t bytes) -> void* {
        void* p = ws + off;
        off = (off + bytes + 511) & ~(size_t)511;
        return p;
    };
    unsigned short* h0b = (unsigned short*)carve((size_t)N * HIDDEN_C * 2);  // 25.6 MB
    unsigned short* bA  = (unsigned short*)carve((size_t)N * HIDDEN_C * 2);  // 25.6 MB
    unsigned short* bB  = (unsigned short*)carve((size_t)N * HIDDEN_C * 2);  // 25.6 MB
    int*   deg     = (int*)  carve((size_t)N * sizeof(int));
    float* dinv    = (float*)carve((size_t)N * sizeof(float));
    int*   offs    = (int*)  carve((size_t)(N + 1) * sizeof(int));
    int*   cursor  = (int*)  carve((size_t)N * sizeof(int));
    uint2* csr     = (uint2*)carve((size_t)E * sizeof(uint2));
    int*   blksum  = (int*)  carve((size_t)SCAN_B * sizeof(int));
    int*   blkoff  = (int*)  carve((size_t)SCAN_B * sizeof(int));
    (void)ws_size;

    hipMemsetAsync(deg, 0, (size_t)N * sizeof(int), stream);

    int eb = (E + 255) / 256;
    k_deg<<<eb, 256, 0, stream>>>(dst, deg, E);
    k_scan_a<<<SCAN_B, 1024, 0, stream>>>(deg, offs, blksum, dinv, N);
    k_scan_b<<<1, 128, 0, stream>>>(blksum, blkoff, offs, SCAN_B, N);
    k_scan_c<<<SCAN_B, 1024, 0, stream>>>(offs, cursor, blkoff, N);
    k_fill<<<eb, 256, 0, stream>>>(src, dst, dinv, cursor, csr, E);

    k_gemm<<<(N + 127) / 128, 256, 0, stream>>>(x, W, b, h0b, N);

    // 10 hops: hops 1..9 write bf16 ping-pong, hop 10 writes fp32 d_out
    const uint4* hin = (const uint4*)h0b;
    for (int k = 0; k < K_HOPS_C; ++k) {
        int fin = (k == K_HOPS_C - 1);
        uint4* houtb = ((k & 1) == 0) ? (uint4*)bA : (uint4*)bB;
        k_prop<<<(N + 3) / 4, 256, 0, stream>>>(hin, (const uint4*)h0b,
                                                fin ? nullptr : houtb,
                                                fin ? out : nullptr,
                                                offs, csr, dinv, N, fin);
        hin = houtb;
    }
}